// Round 11
// baseline (372.021 us; speedup 1.0000x reference)
//
#include <hip/hip_runtime.h>
#include <hip/hip_bf16.h>

typedef __hip_bfloat16 bf16;
typedef short bf16x8_t __attribute__((ext_vector_type(8)));  // 8 bf16 = 4 VGPRs
typedef short s4_t __attribute__((ext_vector_type(4)));      // 4 bf16 = 8B
typedef float f32x4_t __attribute__((ext_vector_type(4)));

#define NTOK 8192
#define INF  1024
#define OUTF 1024
#define GS   8
#define KTOT (INF + INF * GS)  // 9216

union b8u { bf16 h[8]; bf16x8_t v; };
union b4u { bf16 h[4]; ushort2 v2[2]; };
union b4s { bf16 h[4]; s4_t v; };

// ---------------- prep v4: silu (17MB) + exp-PAIRS (67MB) + B ----------------------
// A-spline bf16 (134MB) is GONE: gemm expands fragments from (e^-x, e^x) f32 pairs.
// en/ep are the exact f32 values prep v3 used -> downstream products identical.
#define PA2 NTOK                      // 8192 row blocks
#define PB ((OUTF * INF * 2) / 256)   // 8192 blocks

__global__ __launch_bounds__(256) void prep_fused(const float* __restrict__ x,
                                                  const float* __restrict__ bw,
                                                  const float* __restrict__ sw,
                                                  const float* __restrict__ ss,
                                                  bf16* __restrict__ A,   // silu [n][INF]
                                                  float* __restrict__ E,  // pairs [n][INF]{en,ep}
                                                  bf16* __restrict__ B) {
  const int b = blockIdx.x;
  if (b < PA2) {
    const int n = b;
    #pragma unroll
    for (int j = 0; j < 4; ++j) {
      const int i = threadIdx.x + 256 * j;
      const float xv = x[(size_t)n * INF + i];
      const float en = __expf(-xv);
      const float ep = __expf(xv);
      A[(size_t)n * INF + i] = __float2bfloat16(xv / (1.0f + en));  // SiLU
      ((float2*)E)[(size_t)n * INF + i] = make_float2(en, ep);      // 512B/wave
    }
  } else {
    const int tid = (b - PA2) * 256 + threadIdx.x;  // 0 .. OUTF*INF*2-1
    const int o = tid >> 11;
    const int r = tid & 2047;
    const float4 w4 = ((const float4*)sw)[tid];
    const float sc = ss[tid >> 1];
    b4u r4;
    r4.h[0] = __float2bfloat16(w4.x * sc);
    r4.h[1] = __float2bfloat16(w4.y * sc);
    r4.h[2] = __float2bfloat16(w4.z * sc);
    r4.h[3] = __float2bfloat16(w4.w * sc);
    const size_t rowb = (size_t)o * KTOT;
    *(ushort2*)(B + rowb + INF + (size_t)r * 4)     = r4.v2[0];
    *(ushort2*)(B + rowb + INF + (size_t)r * 4 + 2) = r4.v2[1];
    if ((tid & 1) == 0)
      B[rowb + (r >> 1)] = __float2bfloat16(bw[tid >> 1]);
  }
}

// ---------------- GEMM: C = [silu|spline](x) * B^T, spline A expanded from pairs ---
// R10 base (frag-prefetch dist-1, mid-iter boundary, 3-ring, counted vmcnt, XCD
// remap, k-slice wave pairs; 143.9us verified PASS). Change: for spline tiles
// (kt>=16) A is staged as f32 PAIRS (16KB/tile, 2 gload_lds) and each lane expands
// its bf16x8 frag in-register: frag k-octet = 8 g's of ONE i (k = i*8+g), so
// frag[j] = min(en*EG[j], ep*EIG[j]) from one ds_read_b64. LDS/tile: 144->96KB.
// Base tiles (kt<16): R10 path VERBATIM (bf16 A + XOR swizzle + READ12).
// Ledgers:
//   - stages/tile: base 6, spline 4 (2 pairE + 2 B), none at kt>=142. Mid-iter
//     vmcnt(N) = #stages issued THIS iter (retires tile kt+1's, any count). N is
//     a compile-time flag per BODY.
//   - pair reads (8x b64) + B reads (4x b128) issue at mid; expansion after MFMA
//     cluster1, waits via compiler-tracked lgkm deps; end-iter lgkm(0) covers B.
//   - WAR ring + cross-wave publication: unchanged from R10 (barrier-separated).
//   - pair-read banks: addr/4 = row*16+islot*2; 64 lanes -> balanced multi-sweep.
#define BM 256
#define BN 128
#define BK 64
#define NT (KTOT / BK)            // 144
#define NBASE (INF / BK)          // 16
#define LDSA (BM * BK * 2)        // 32768 B (base bf16 tile; pairs use first 16KB)
#define LDSB (BN * BK * 2)        // 16384 B
#define LDSBUF (LDSA + LDSB)      // 49152 B

__global__ __launch_bounds__(512) void gemm_bt2(const bf16* __restrict__ A,
                                                const float* __restrict__ E,
                                                const bf16* __restrict__ B,
                                                float* __restrict__ C) {
  __shared__ __align__(16) char smem[3 * LDSBUF];   // 144 KB ring (+epilogue merge)
  const int t = threadIdx.x;
  const int lane = t & 63;
  const int w = t >> 6;            // wave 0..7
  const int q = w & 3;             // quadrant 0..3 (2M x 2N of 128x64)
  const int s = w >> 2;            // k-slice 0/1 (kk = s*32)
  const int wm = (q >> 1) * 128;   // 0,128
  const int wn = (q & 1) * 64;     // 0,64
  const int lid = blockIdx.y * 8 + blockIdx.x;     // XCD remap (verified)
  const int br = (lid & 7) * 4 + ((lid >> 3) & 3); // M tile (0..31)
  const int bc = lid >> 5;                         // N tile (0..7)

  const int srow = t >> 3;                         // 0..63
  const int scol = ((t & 7) ^ (srow & 7)) * 8;     // swizzled source k-off (elems)
  const bf16* gA = A + (size_t)(br * BM + srow) * INF + scol;    // silu stride INF
  const bf16* gB = B + (size_t)(bc * BN + srow) * KTOT + scol;
  // pair staging: granule g=(row,p): inst0 rows 0..127 (row=t>>2, p=t&3), inst1 +128.
  const float* gE0 = E + ((size_t)(br * BM + (t >> 2)) * INF + (t & 3) * 2) * 2;
  const float* gE1 = gE0 + (size_t)128 * INF * 2;
  const int wb = w * 1024;

  // fragment addressing (verified; k-base wave-uniform s*32)
  const int frow = lane & 15;
  const int fk = (lane >> 4) * 8;
  const int fsw = frow & 7;
  const int swk = ((((s << 5) + fk) >> 3) ^ fsw) * 8;
  const int islot = s * 4 + (lane >> 4);           // i-octet within spline tile

  const float EG[8]  = {0.36787944f, 0.47236655f, 0.60653066f, 0.77880078f,
                        1.0f, 1.28402542f, 1.64872127f, 2.11700002f};   // e^{g_v}
  const float EIG[8] = {2.71828183f, 2.11700002f, 1.64872127f, 1.28402542f,
                        1.0f, 0.77880078f, 0.60653066f, 0.47236655f};   // e^{-g_v}

  f32x4_t acc[8][4] = {};
  bf16x8_t aLE[4], aHE[4], bE[4];   // frag set E (even tiles)
  bf16x8_t aLO[4], aHO[4], bO[4];   // frag set O (odd tiles)

#define STAGE_A(b_, i_, kt_) \
  __builtin_amdgcn_global_load_lds( \
      (const __attribute__((address_space(1))) void*)(gA + (size_t)(i_) * 64 * INF + (size_t)(kt_) * BK), \
      (__attribute__((address_space(3))) void*)(smem + (b_) * LDSBUF + (i_) * 8192 + wb), 16, 0, 0)
#define STAGE_B(b_, i_, kt_) \
  __builtin_amdgcn_global_load_lds( \
      (const __attribute__((address_space(1))) void*)(gB + (size_t)(i_) * 64 * KTOT + (size_t)(kt_) * BK), \
      (__attribute__((address_space(3))) void*)(smem + (b_) * LDSBUF + LDSA + (i_) * 8192 + wb), 16, 0, 0)
#define STAGE6(b_, kt_) do { \
    STAGE_A(b_, 0, kt_); STAGE_A(b_, 1, kt_); \
    STAGE_A(b_, 2, kt_); STAGE_A(b_, 3, kt_); \
    STAGE_B(b_, 0, kt_); STAGE_B(b_, 1, kt_); \
  } while (0)
// spline: A-pairs, 16KB = 2 insts; LDS layout [row 256][ipair 8]{en,ep} (64B rows)
#define STAGEP(b_, kt_) do { \
    __builtin_amdgcn_global_load_lds( \
      (const __attribute__((address_space(1))) void*)(gE0 + (size_t)((kt_) - NBASE) * 16), \
      (__attribute__((address_space(3))) void*)(smem + (b_) * LDSBUF + t * 16), 16, 0, 0); \
    __builtin_amdgcn_global_load_lds( \
      (const __attribute__((address_space(1))) void*)(gE1 + (size_t)((kt_) - NBASE) * 16), \
      (__attribute__((address_space(3))) void*)(smem + (b_) * LDSBUF + 8192 + t * 16), 16, 0, 0); \
    STAGE_B(b_, 0, (kt_)); STAGE_B(b_, 1, (kt_)); \
  } while (0)

#define READ12(buf_, AL_, AH_, BB_) do { \
    const bf16* sAr_ = (const bf16*)(smem + (buf_) * LDSBUF); \
    const bf16* sBr_ = (const bf16*)(smem + (buf_) * LDSBUF + LDSA); \
    _Pragma("unroll") \
    for (int i = 0; i < 4; ++i) { \
      AL_[i] = *(const bf16x8_t*)(sAr_ + (wm + i * 16 + frow) * BK + swk); \
      BB_[i] = *(const bf16x8_t*)(sBr_ + (wn + i * 16 + frow) * BK + swk); \
    } \
    _Pragma("unroll") \
    for (int i = 0; i < 4; ++i) \
      AH_[i] = *(const bf16x8_t*)(sAr_ + (wm + 64 + i * 16 + frow) * BK + swk); \
  } while (0)

// BODY flags: STG_: 0=base6(vmcnt6) 1=spline4(vmcnt4) 2=none(vmcnt0); RD_: 0=base
// 1=pair+expand 2=none. All literals -> folded.
#define BODY(KT_, STG_, RD_, CL_, CH_, CBv_, NL_, NH_, NBv_) do {                  \
    const int pb = (cb == 0) ? 2 : cb - 1;                                         \
    const int nb = (cb == 2) ? 0 : cb + 1;                                         \
    if (STG_ == 0) STAGE6(pb, (KT_) + 2);                                          \
    else if (STG_ == 1) STAGEP(pb, (KT_) + 2);                                     \
    __builtin_amdgcn_s_setprio(1);                                                 \
    _Pragma("unroll")                                                              \
    for (int i = 0; i < 4; ++i)                                                    \
      _Pragma("unroll")                                                            \
      for (int j = 0; j < 4; ++j)                                                  \
        acc[i][j] = __builtin_amdgcn_mfma_f32_16x16x32_bf16(CL_[i], CBv_[j], acc[i][j], 0, 0, 0); \
    __builtin_amdgcn_s_setprio(0);                                                 \
    float2 pv[8];                                                                  \
    if (RD_ != 2) {                                                                \
      if (STG_ == 0)      { asm volatile("s_waitcnt vmcnt(6)" ::: "memory"); }     \
      else if (STG_ == 1) { asm volatile("s_waitcnt vmcnt(4)" ::: "memory"); }     \
      else                { asm volatile("s_waitcnt vmcnt(0)" ::: "memory"); }     \
      __builtin_amdgcn_s_barrier();                                                \
      __builtin_amdgcn_sched_barrier(0);  /* reads stay AFTER barrier */           \
      if (RD_ == 0) { READ12(nb, NL_, NH_, NBv_); }                                \
      else {                                                                       \
        const float* pA_ = (const float*)(smem + nb * LDSBUF);                     \
        _Pragma("unroll")                                                          \
        for (int f = 0; f < 8; ++f)                                                \
          pv[f] = *(const float2*)(pA_ + (wm + f * 16 + frow) * 16 + islot * 2);   \
        __builtin_amdgcn_sched_barrier(0);                                         \
        const bf16* sBr_ = (const bf16*)(smem + nb * LDSBUF + LDSA);               \
        _Pragma("unroll")                                                          \
        for (int i = 0; i < 4; ++i)                                                \
          NBv_[i] = *(const bf16x8_t*)(sBr_ + (wn + i * 16 + frow) * BK + swk);    \
      }                                                                            \
    }                                                                              \
    __builtin_amdgcn_s_setprio(1);                                                 \
    _Pragma("unroll")                                                              \
    for (int i = 0; i < 4; ++i)                                                    \
      _Pragma("unroll")                                                            \
      for (int j = 0; j < 4; ++j)                                                  \
        acc[i + 4][j] = __builtin_amdgcn_mfma_f32_16x16x32_bf16(CH_[i], CBv_[j], acc[i + 4][j], 0, 0, 0); \
    __builtin_amdgcn_s_setprio(0);                                                 \
    if (RD_ == 1) {  /* expand pairs -> next A frags (compiler waits pair lgkm) */ \
      _Pragma("unroll")                                                            \
      for (int f = 0; f < 8; ++f) {                                                \
        const float en_ = pv[f].x, ep_ = pv[f].y;                                  \
        b8u pk_;                                                                   \
        _Pragma("unroll")                                                          \
        for (int g = 0; g < 8; ++g)                                                \
          pk_.h[g] = __float2bfloat16(fminf(en_ * EG[g], ep_ * EIG[g]));           \
        if (f < 4) NL_[f] = pk_.v; else NH_[f - 4] = pk_.v;                        \
      }                                                                            \
    }                                                                              \
    asm volatile("s_waitcnt lgkmcnt(0)" ::: "memory");                             \
    __builtin_amdgcn_sched_barrier(0);                                             \
    cb = nb;                                                                       \
  } while (0)

  // prologue: stage tiles 0,1 (base); publish tile 0; preload frags(0) -> set E
  STAGE6(0, 0);
  STAGE6(1, 1);
  asm volatile("s_waitcnt vmcnt(6)" ::: "memory");
  __builtin_amdgcn_s_barrier();
  __builtin_amdgcn_sched_barrier(0);
  READ12(0, aLE, aHE, bE);
  asm volatile("s_waitcnt lgkmcnt(0)" ::: "memory");
  __builtin_amdgcn_sched_barrier(0);

  int cb = 0;
  for (int kt = 0; kt < 14; kt += 2) {           // tiles 0..13: base/base
    BODY(kt,     0, 0, aLE, aHE, bE, aLO, aHO, bO);
    BODY(kt + 1, 0, 0, aLO, aHO, bO, aLE, aHE, bE);
  }
  BODY(14, 1, 0, aLE, aHE, bE, aLO, aHO, bO);    // stage 16 pair, read 15 base
  BODY(15, 1, 1, aLO, aHO, bO, aLE, aHE, bE);    // stage 17 pair, read 16 pair
  for (int kt = 16; kt < 142; kt += 2) {         // tiles 16..141: pair/pair
    BODY(kt,     1, 1, aLE, aHE, bE, aLO, aHO, bO);
    BODY(kt + 1, 1, 1, aLO, aHO, bO, aLE, aHE, bE);
  }
  BODY(142, 2, 1, aLE, aHE, bE, aLO, aHO, bO);   // no stage, read 143 pair
  BODY(143, 2, 2, aLO, aHO, bO, aLE, aHE, bE);   // last

  // ---- epilogue: merge k-slice pairs via LDS ----
  __syncthreads();   // all waves done with ring reads before overwrite
  if (s == 1) {
    char* dst = smem + q * 32768;
    #pragma unroll
    for (int i = 0; i < 8; ++i)
      #pragma unroll
      for (int j = 0; j < 4; ++j)
        *(f32x4_t*)(dst + ((i * 4 + j) * 64 + lane) * 16) = acc[i][j];
  }
  __syncthreads();
  if (s == 0) {
    const char* src = smem + q * 32768;
    #pragma unroll
    for (int i = 0; i < 8; ++i)
      #pragma unroll
      for (int j = 0; j < 4; ++j) {
        const f32x4_t p = *(const f32x4_t*)(src + ((i * 4 + j) * 64 + lane) * 16);
        acc[i][j] += p;
      }
    // D mapping col = lane&15, row = (lane>>4)*4 + reg  [m89/m91]
    const int ccol = bc * BN + wn + frow;
    const int crow0 = br * BM + wm + (lane >> 4) * 4;
    #pragma unroll
    for (int i = 0; i < 8; ++i)
      #pragma unroll
      for (int r = 0; r < 4; ++r) {
        float* cp = C + (size_t)(crow0 + i * 16 + r) * OUTF + ccol;
        #pragma unroll
        for (int j = 0; j < 4; ++j)
          cp[j * 16] = acc[i][j][r];
      }
  }
#undef STAGE_A
#undef STAGE_B
#undef STAGE6
#undef STAGEP
#undef READ12
#undef BODY
}

// ---------------- fallback (ws too small): naive, correctness-only ----------------
__global__ __launch_bounds__(256) void naive_kern(const float* __restrict__ x,
                                                  const float* __restrict__ bw,
                                                  const float* __restrict__ sw,
                                                  const float* __restrict__ ss,
                                                  const float* __restrict__ grid,
                                                  float* __restrict__ out) {
  const int idx = blockIdx.x * 256 + threadIdx.x;  // n*OUTF + o
  const int o = idx & (OUTF - 1);
  const int n = idx >> 10;
  float acc = 0.f;
  for (int i = 0; i < INF; ++i) {
    const float xv = x[n * INF + i];
    const float s = xv / (1.f + __expf(-xv));
    acc += s * bw[o * INF + i];
    const float sc = ss[o * INF + i];
    #pragma unroll
    for (int g = 0; g < 8; ++g) {
      const float gv = grid[i * 8 + g];
      acc += __expf(-fabsf(xv - gv)) * sw[(size_t)(o * INF + i) * 8 + g] * sc;
    }
  }
  out[idx] = acc;
}

extern "C" void kernel_launch(void* const* d_in, const int* in_sizes, int n_in,
                              void* d_out, int out_size, void* d_ws, size_t ws_size,
                              hipStream_t stream) {
  const float* x    = (const float*)d_in[0];
  const float* bw   = (const float*)d_in[1];
  const float* sw   = (const float*)d_in[2];
  const float* ss   = (const float*)d_in[3];
  const float* grid = (const float*)d_in[4];
  float* out = (float*)d_out;

  const size_t needAs = (size_t)NTOK * INF * sizeof(bf16);   // ~16.8 MB silu
  const size_t needE  = (size_t)NTOK * INF * 8;              // ~67.1 MB pairs
  const size_t needB  = (size_t)OUTF * KTOT * sizeof(bf16);  // ~18.9 MB

  if (ws_size >= needAs + needE + needB) {
    bf16*  A = (bf16*)d_ws;
    float* E = (float*)((char*)d_ws + needAs);
    bf16*  B = (bf16*)((char*)d_ws + needAs + needE);
    prep_fused<<<PA2 + PB, 256, 0, stream>>>(x, bw, sw, ss, A, E, B);
    dim3 g(OUTF / BN, NTOK / BM);  // (8, 32) = 256 blocks = 1/CU
    gemm_bt2<<<g, 512, 0, stream>>>(A, E, B, out);
  } else {
    naive_kern<<<(NTOK * OUTF) / 256, 256, 0, stream>>>(x, bw, sw, ss, grid, out);
  }
}